// Round 13
// baseline (158.685 us; speedup 1.0000x reference)
//
#include <hip/hip_runtime.h>
#include <math.h>

#define P 4096
#define NB 2
#define NROWS (NB * P)                // 8192
#define THREADS 512
#define NWAVE (THREADS / 64)          // 8
#define R0 8                          // rows per block: lse0 / col_final
#define RP 16                         // rows per block: plain sweeps (rows in SGPR)
#define RF 4                          // rows per block: row_final (heavy acc)
#define NCHUNK (P / THREADS)          // 8 columns per thread
#define SQRT_LOG2E 1.2011224087864498f
#define LOG2_INV_P (-12.0f)           // log2(1/4096)
#define ERR_T2 0.028853900817779268f  // 0.02 / ln2
#define C_DIST 1.6922538540598323e-4f // ln(2)/4096
#define NBUCKET 32
#define BSTRIDE 16                    // floats; 64B cacheline padding

// ws float layout:
//   u2[8192]@0, v2[8192]@8192,
//   errA@16384, errB@16896, distB@17408  (32 padded slots each)
//   SoA float4 @17920: rowQX, rowQY(+32768), colQX(+65536), colQY(+98304)
//     rowQ = (s*c0, s*c1, s*c2, n);  colQ = (2s*c0, 2s*c1, 2s*c2, n)
#define WS_U    0
#define WS_V    NROWS
#define WS_ERRA 16384
#define WS_ERRB 16896
#define WS_DSTB 17408
#define WS_SOA  17920

// d_out (floats): [0]=distance, [1..8192]=corr1, [8193..16384]=corr2
//
// Lessons carried: R8 cooperative launch breaks graph capture; R10 full-grid
// sw barrier deadlocks -> sync ONLY at dispatch boundaries. R4-R6:
// launch_bounds min-blocks clamps VGPR -> spill; never pass it. R11: bucketed
// atomics. R12: buckets accumulate onto 0xAA poison (-3e-13/slot, negligible).
// R13: block-uniform row data forced to SGPRs (readfirstlane) -> VGPR<=64 ->
// 8 waves/SIMD; R rebalanced per kernel (16 sweeps / 4 row_final).

__device__ __forceinline__ float exp2_hw(float x) {
    float r;
    asm("v_exp_f32 %0, %1" : "=v"(r) : "v"(x));   // 2^x, single instr
    return r;
}
__device__ __forceinline__ float sread(float v) {  // force value into SGPR
    return __int_as_float(__builtin_amdgcn_readfirstlane(__float_as_int(v)));
}

__device__ __forceinline__ float bucket_sum(const float* p) {
    float s = 0.0f;
#pragma unroll
    for (int i = 0; i < NBUCKET; i++) s += p[i * BSTRIDE];
    return s;   // fixed order -> identical (uniform) decision in every block
}

// ---------------- i=0: from raw x,y + SoA production (R0=8, grid 1024) -----
__global__ __launch_bounds__(THREADS) void lse0(
    const float* __restrict__ x, const float* __restrict__ y,
    float* __restrict__ ws)
{
    float4* __restrict__ rowQX = (float4*)(ws + WS_SOA);
    float4* __restrict__ rowQY = (float4*)(ws + WS_SOA + 32768);
    float4* __restrict__ colQX = (float4*)(ws + WS_SOA + 65536);
    float4* __restrict__ colQY = (float4*)(ws + WS_SOA + 98304);
    float* __restrict__ u2 = ws + WS_U;
    float* __restrict__ v2 = ws + WS_V;
    float* __restrict__ errA = ws + WS_ERRA;

    __shared__ float red[NWAVE * R0];

    const int row0 = blockIdx.x * R0;
    const int bofs = (row0 >> 12) << 12;
    const int t = threadIdx.x;
    const int wid = t >> 6, lane = t & 63;

    // SoA production for rows [row0, row0+R0) of BOTH point sets.
    if (t < R0) {
        const int rr = row0 + t;
        const float a0 = x[rr * 3 + 0] * SQRT_LOG2E;
        const float a1 = x[rr * 3 + 1] * SQRT_LOG2E;
        const float a2 = x[rr * 3 + 2] * SQRT_LOG2E;
        const float an = a0 * a0 + a1 * a1 + a2 * a2;
        rowQX[rr] = make_float4(a0, a1, a2, an);
        colQX[rr] = make_float4(a0 + a0, a1 + a1, a2 + a2, an);
        const float b0 = y[rr * 3 + 0] * SQRT_LOG2E;
        const float b1 = y[rr * 3 + 1] * SQRT_LOG2E;
        const float b2 = y[rr * 3 + 2] * SQRT_LOG2E;
        const float bn = b0 * b0 + b1 * b1 + b2 * b2;
        rowQY[rr] = make_float4(b0, b1, b2, bn);
        colQY[rr] = make_float4(b0 + b0, b1 + b1, b2 + b2, bn);
        v2[rr] = 0.0f;                 // reference init state for v
    }

    float r0[R0], r1[R0], r2[R0], rnm[R0];   // SGPR-resident (uniform)
#pragma unroll
    for (int r = 0; r < R0; r++) {
        const int rr = row0 + r;
        const float a0 = x[rr * 3 + 0] * SQRT_LOG2E;
        const float a1 = x[rr * 3 + 1] * SQRT_LOG2E;
        const float a2 = x[rr * 3 + 2] * SQRT_LOG2E;
        const float an = a0 * a0 + a1 * a1 + a2 * a2;
        r0[r] = sread(a0); r1[r] = sread(a1); r2[r] = sread(a2); rnm[r] = sread(an);
    }
    float q0[NCHUNK], q1[NCHUNK], q2[NCHUNK], aa[NCHUNK];
#pragma unroll
    for (int k = 0; k < NCHUNK; k++) {
        const int j = bofs + t + k * THREADS;
        const float b0 = y[j * 3 + 0] * SQRT_LOG2E;
        const float b1 = y[j * 3 + 1] * SQRT_LOG2E;
        const float b2 = y[j * 3 + 2] * SQRT_LOG2E;
        const float bn = b0 * b0 + b1 * b1 + b2 * b2;
        q0[k] = b0 + b0;
        q1[k] = b1 + b1;
        q2[k] = b2 + b2;
        aa[k] = 0.0f - bn;             // w == 0 at i=0
    }

    float s[R0];
#pragma unroll
    for (int r = 0; r < R0; r++) s[r] = 0.0f;
#pragma unroll
    for (int k = 0; k < NCHUNK; k++) {
#pragma unroll
        for (int r = 0; r < R0; r++) {
            const float b = aa[k] - rnm[r];
            const float m2 = fmaf(q0[k], r0[r], fmaf(q1[k], r1[r], fmaf(q2[k], r2[r], b)));
            s[r] += exp2_hw(m2);
        }
    }
#pragma unroll
    for (int r = 0; r < R0; r++) {
        float v = s[r];
#pragma unroll
        for (int off = 32; off >= 1; off >>= 1)
            v += __shfl_down(v, off, 64);
        if (lane == 0) red[wid * R0 + r] = v;
    }
    __syncthreads();
    if (t < R0) {
        float ssum = red[t];
#pragma unroll
        for (int w = 1; w < NWAVE; w++) ssum += red[w * R0 + t];
        const float pn = LOG2_INV_P - __log2f(ssum);
        float d = fabsf(pn - 0.0f);    // old u == 0
        u2[row0 + t] = pn;
#pragma unroll
        for (int off = R0 / 2; off >= 1; off >>= 1)
            d += __shfl_down(d, off, R0);
        if (t == 0)
            atomicAdd(&errA[(blockIdx.x & (NBUCKET - 1)) * BSTRIDE], d);
    }
}

// ---------------- gated packed-SoA lse (i = 1,2,3; RP=16, grid 512) --------
template <int WITH_ERR>
__global__ __launch_bounds__(THREADS) void lse_p(
    const float4* __restrict__ rowQ, const float4* __restrict__ colQ,
    const float* __restrict__ w2, float* __restrict__ pot2,
    float* __restrict__ err_bkt,
    const float* __restrict__ chk0, const float* __restrict__ chk1)
{
    bool frozen = false;
    if (chk0) frozen = frozen || (bucket_sum(chk0) < ERR_T2);
    if (chk1) frozen = frozen || (bucket_sum(chk1) < ERR_T2);
    if (frozen) return;  // uniform across grid

    __shared__ float red[NWAVE * RP];

    const int row0 = blockIdx.x * RP;
    const int bofs = (row0 >> 12) << 12;
    const int t = threadIdx.x;
    const int wid = t >> 6, lane = t & 63;

    float r0[RP], r1[RP], r2[RP], rnm[RP];   // SGPR-resident (uniform)
#pragma unroll
    for (int r = 0; r < RP; r++) {
        const float4 rq = rowQ[row0 + r];
        r0[r] = sread(rq.x); r1[r] = sread(rq.y);
        r2[r] = sread(rq.z); rnm[r] = sread(rq.w);
    }
    float q0[NCHUNK], q1[NCHUNK], q2[NCHUNK], aa[NCHUNK];
#pragma unroll
    for (int k = 0; k < NCHUNK; k++) {
        const int j = bofs + t + k * THREADS;
        const float4 q = colQ[j];
        q0[k] = q.x; q1[k] = q.y; q2[k] = q.z;
        aa[k] = w2[j] - q.w;
    }

    float s[RP];
#pragma unroll
    for (int r = 0; r < RP; r++) s[r] = 0.0f;
#pragma unroll
    for (int k = 0; k < NCHUNK; k++) {
#pragma unroll
        for (int r = 0; r < RP; r++) {
            const float b = aa[k] - rnm[r];
            const float m2 = fmaf(q0[k], r0[r], fmaf(q1[k], r1[r], fmaf(q2[k], r2[r], b)));
            s[r] += exp2_hw(m2);
        }
    }
#pragma unroll
    for (int r = 0; r < RP; r++) {
        float v = s[r];
#pragma unroll
        for (int off = 32; off >= 1; off >>= 1)
            v += __shfl_down(v, off, 64);
        if (lane == 0) red[wid * RP + r] = v;
    }
    __syncthreads();
    if (t < RP) {
        float ssum = red[t];
#pragma unroll
        for (int w = 1; w < NWAVE; w++) ssum += red[w * RP + t];
        const float pn = LOG2_INV_P - __log2f(ssum);
        float d = 0.0f;
        if (WITH_ERR) d = fabsf(pn - pot2[row0 + t]);
        pot2[row0 + t] = pn;
        if (WITH_ERR) {
#pragma unroll
            for (int off = RP / 2; off >= 1; off >>= 1)
                d += __shfl_down(d, off, RP);
            if (t == 0)
                atomicAdd(&err_bkt[(blockIdx.x & (NBUCKET - 1)) * BSTRIDE], d);
        }
    }
}

// ---------------- row_final: lse#5 + corr1 + distance (RF=4, grid 2048) ----
__global__ __launch_bounds__(THREADS) void row_final(
    const float4* __restrict__ rowQ, const float4* __restrict__ colQ,
    const float* __restrict__ w2, float* __restrict__ u2_out,
    float* __restrict__ corr1, float* __restrict__ dist_bkt)
{
    __shared__ float redS[NWAVE * RF];
    __shared__ float redD[NWAVE * RF];
    __shared__ float redv[NWAVE * RF];
    __shared__ int   redj[NWAVE * RF];

    const int row0 = blockIdx.x * RF;
    const int bofs = (row0 >> 12) << 12;
    const int t = threadIdx.x;
    const int wid = t >> 6, lane = t & 63;

    float r0[RF], r1[RF], r2[RF], rnm[RF];   // SGPR-resident
#pragma unroll
    for (int r = 0; r < RF; r++) {
        const float4 rq = rowQ[row0 + r];
        r0[r] = sread(rq.x); r1[r] = sread(rq.y);
        r2[r] = sread(rq.z); rnm[r] = sread(rq.w);
    }
    float q0[NCHUNK], q1[NCHUNK], q2[NCHUNK], aa[NCHUNK], wv[NCHUNK];
#pragma unroll
    for (int k = 0; k < NCHUNK; k++) {
        const int j = bofs + t + k * THREADS;
        const float4 q = colQ[j];
        q0[k] = q.x; q1[k] = q.y; q2[k] = q.z;
        wv[k] = w2[j];
        aa[k] = wv[k] - q.w;
    }

    float S[RF], D[RF], bv[RF];
    int bj[RF];
#pragma unroll
    for (int r = 0; r < RF; r++) { S[r] = 0.0f; D[r] = 0.0f; bv[r] = -INFINITY; bj[r] = 0; }

#pragma unroll
    for (int k = 0; k < NCHUNK; k++) {
#pragma unroll
        for (int r = 0; r < RF; r++) {
            const float b = aa[k] - rnm[r];
            const float m2 = fmaf(q0[k], r0[r], fmaf(q1[k], r1[r], fmaf(q2[k], r2[r], b)));
            const float e = exp2_hw(m2);
            S[r] += e;
            D[r] = fmaf(e, wv[k] - m2, D[r]);     // (v2 - m2) = log2e*C >= 0
            const bool pgt = m2 > bv[r];          // strict >, k ascending -> first max
            bj[r] = pgt ? (t + k * THREADS) : bj[r];
            bv[r] = pgt ? m2 : bv[r];
        }
    }
#pragma unroll
    for (int r = 0; r < RF; r++) {
        float sS = S[r], sD = D[r], v2 = bv[r];
        int j2 = bj[r];
#pragma unroll
        for (int off = 32; off >= 1; off >>= 1) {
            sS += __shfl_down(sS, off, 64);
            sD += __shfl_down(sD, off, 64);
            const float ov = __shfl_down(v2, off, 64);
            const int   oj = __shfl_down(j2, off, 64);
            const bool take = (ov > v2) || (ov == v2 && oj < j2);
            v2 = take ? ov : v2;
            j2 = take ? oj : j2;
        }
        if (lane == 0) {
            redS[wid * RF + r] = sS;
            redD[wid * RF + r] = sD;
            redv[wid * RF + r] = v2;
            redj[wid * RF + r] = j2;
        }
    }
    __syncthreads();
    if (t < RF) {
        float sS = redS[t], sD = redD[t], v2 = redv[t];
        int j2 = redj[t];
#pragma unroll
        for (int w = 1; w < NWAVE; w++) {
            sS += redS[w * RF + t];
            sD += redD[w * RF + t];
            const float ov = redv[w * RF + t];
            const int   oj = redj[w * RF + t];
            const bool take = (ov > v2) || (ov == v2 && oj < j2);
            v2 = take ? ov : v2;
            j2 = take ? oj : j2;
        }
        u2_out[row0 + t] = LOG2_INV_P - __log2f(sS);
        corr1[row0 + t] = (float)j2;
        float dp = C_DIST * sD / sS;
#pragma unroll
        for (int off = RF / 2; off >= 1; off >>= 1)
            dp += __shfl_down(dp, off, RF);
        if (t == 0)
            atomicAdd(&dist_bkt[(blockIdx.x & (NBUCKET - 1)) * BSTRIDE], dp);
    }
}

// ---------------- col_final: corr2 + distance finalize (R0=8, grid 1024) ---
__global__ __launch_bounds__(THREADS) void col_final(
    const float4* __restrict__ rowQ, const float4* __restrict__ colQ,
    const float* __restrict__ w2, float* __restrict__ corr2,
    const float* __restrict__ dist_bkt, float* __restrict__ dist_out)
{
    __shared__ float redv[NWAVE * R0];
    __shared__ int   redj[NWAVE * R0];

    const int row0 = blockIdx.x * R0;
    const int bofs = (row0 >> 12) << 12;
    const int t = threadIdx.x;
    const int wid = t >> 6, lane = t & 63;

    float r0[R0], r1[R0], r2[R0], rnm[R0];   // SGPR-resident
#pragma unroll
    for (int r = 0; r < R0; r++) {
        const float4 rq = rowQ[row0 + r];
        r0[r] = sread(rq.x); r1[r] = sread(rq.y);
        r2[r] = sread(rq.z); rnm[r] = sread(rq.w);
    }
    float q0[NCHUNK], q1[NCHUNK], q2[NCHUNK], aa[NCHUNK];
#pragma unroll
    for (int k = 0; k < NCHUNK; k++) {
        const int j = bofs + t + k * THREADS;
        const float4 q = colQ[j];
        q0[k] = q.x; q1[k] = q.y; q2[k] = q.z;
        aa[k] = w2[j] - q.w;
    }

    float bv[R0];
    int bj[R0];
#pragma unroll
    for (int r = 0; r < R0; r++) { bv[r] = -INFINITY; bj[r] = 0; }

#pragma unroll
    for (int k = 0; k < NCHUNK; k++) {
#pragma unroll
        for (int r = 0; r < R0; r++) {
            const float b = aa[k] - rnm[r];
            const float m2 = fmaf(q0[k], r0[r], fmaf(q1[k], r1[r], fmaf(q2[k], r2[r], b)));
            const bool pgt = m2 > bv[r];
            bj[r] = pgt ? (t + k * THREADS) : bj[r];
            bv[r] = pgt ? m2 : bv[r];
        }
    }
#pragma unroll
    for (int r = 0; r < R0; r++) {
        float v2 = bv[r];
        int j2 = bj[r];
#pragma unroll
        for (int off = 32; off >= 1; off >>= 1) {
            const float ov = __shfl_down(v2, off, 64);
            const int   oj = __shfl_down(j2, off, 64);
            const bool take = (ov > v2) || (ov == v2 && oj < j2);
            v2 = take ? ov : v2;
            j2 = take ? oj : j2;
        }
        if (lane == 0) { redv[wid * R0 + r] = v2; redj[wid * R0 + r] = j2; }
    }
    __syncthreads();
    if (t < R0) {
        float v2 = redv[t];
        int j2 = redj[t];
#pragma unroll
        for (int w = 1; w < NWAVE; w++) {
            const float ov = redv[w * R0 + t];
            const int   oj = redj[w * R0 + t];
            const bool take = (ov > v2) || (ov == v2 && oj < j2);
            v2 = take ? ov : v2;
            j2 = take ? oj : j2;
        }
        corr2[row0 + t] = (float)j2;
    }
    if (blockIdx.x == 0 && t == 0) *dist_out = bucket_sum(dist_bkt);
}

extern "C" void kernel_launch(void* const* d_in, const int* in_sizes, int n_in,
                              void* d_out, int out_size, void* d_ws, size_t ws_size,
                              hipStream_t stream) {
    const float* x = (const float*)d_in[0];   // (2, 4096, 3) f32
    const float* y = (const float*)d_in[1];   // (2, 4096, 3) f32
    float* out = (float*)d_out;               // 1 + 8192 + 8192 floats
    float* ws = (float*)d_ws;

    float* u2 = ws + WS_U;
    float* v2 = ws + WS_V;
    float* errA = ws + WS_ERRA;
    float* errB = ws + WS_ERRB;
    float* dstB = ws + WS_DSTB;
    const float4* rowQX = (const float4*)(ws + WS_SOA);
    const float4* rowQY = (const float4*)(ws + WS_SOA + 32768);
    const float4* colQX = (const float4*)(ws + WS_SOA + 65536);
    const float4* colQY = (const float4*)(ws + WS_SOA + 98304);

    dim3 blk(THREADS);
    // i=0: u2 = f(v==0) from raw x,y; writes SoA + v2=0 + errA
    lse0<<<dim3(NROWS / R0), blk, 0, stream>>>(x, y, ws);
    // i=1: v2 = g(u2); frozen iff sum(errA)<T
    lse_p<0><<<dim3(NROWS / RP), blk, 0, stream>>>(rowQY, colQX, u2, v2,
                                                   nullptr, errA, nullptr);
    // i=2: u2 = f(v2), errB; frozen iff sum(errA)<T
    lse_p<1><<<dim3(NROWS / RP), blk, 0, stream>>>(rowQX, colQY, v2, u2,
                                                   errB, errA, nullptr);
    // i=3: v2 = g(u2); frozen iff sum(errA)<T | sum(errB)<T
    lse_p<0><<<dim3(NROWS / RP), blk, 0, stream>>>(rowQY, colQX, u2, v2,
                                                   nullptr, errA, errB);
    // i=4 fused into row_final (u_final == f(v_final) in every freeze case)
    row_final<<<dim3(NROWS / RF), blk, 0, stream>>>(rowQX, colQY, v2, u2,
                                                    out + 1, dstB);
    col_final<<<dim3(NROWS / R0), blk, 0, stream>>>(rowQY, colQX, u2,
                                                    out + 1 + NROWS, dstB, out);
}